// Round 10
// baseline (174.078 us; speedup 1.0000x reference)
//
#include <hip/hip_runtime.h>
#include <hip/hip_bf16.h>

// ---------------------------------------------------------------------------
// Causal MHA forward.  B=2, T=2048, H=16, Dk=64, D=1024.  Inputs float32;
// internal pipeline bf16 MFMA.
// R22: R18's dbuf attn resurrected with the conflict bug fixed.  R18 (dbuf
//     K/V, ONE barrier/tile, GLD-prefetch-before-compute, quarter-Ps) hit
//     42.4us ~= R16 but carried PSQ=40 (80B stride -> (l16*20)%32 = 8-way
//     bank conflict, 532K->1.6M conflicts, VALUBusy 34.6%).  PSQ=56: 112B
//     stride -> (l16*28)%32 period-8 = 2-way (free, m136); 56%8==0 keeps
//     ds_read_b128 16B-aligned (PSQ=36 would misalign odd rows).  LDS
//     64K dbuf + 14.3K Ps = 78.3KB -> 2 blocks/CU kept.  Attn otherwise
//     byte-identical to R18's HW-verified kernel.
//     Calibration from R21: cross-pod noise band ~±3.5us (same source:
//     164.9 vs 171.7).  prep/gemm128 frozen at R12 (default x-fastest
//     mapping pins 1MB A-slice/XCD -- do NOT remap, R20); gemm_out at R16.
//     launch_bounds min-waves MUST stay 4 (6 spilled twice: R6, R7).
// Workspace (u16 elements, 1M = 2^20), 40 MB:
//   [0,4M)   Xbf [4096][1024] bf16      (Ab aliases this after QKV)
//   [4M,7M)  Wqkv^T (3 x [1024][1024])
//   [7M,11M) Q   [11M,15M) K   [15M,19M) V^T [32][64][2048]
//   [19M,20M) Wo^T
// ---------------------------------------------------------------------------

typedef unsigned short u16;
typedef __bf16 bf16x8 __attribute__((ext_vector_type(8)));
typedef float f32x4 __attribute__((ext_vector_type(4)));
typedef u16 u16x4 __attribute__((ext_vector_type(4)));

#define TS 72               // padded LDS stride (transpose)
#define PSQ 56              // quarter P-tile stride: 32 cols + 24 pad
                            // (112B row: 2-way banks = free; 16B-aligned)
#define NEG_INF (-1e30f)
#define SC_LOG2 0.1803368801f   // log2(e)/8  (exp2-domain softmax scale)

#if __has_builtin(__builtin_amdgcn_exp2f)
#define EXP2(x) __builtin_amdgcn_exp2f(x)
#else
#define EXP2(x) exp2f(x)
#endif

#define GLD_LDS16(gp, lp) __builtin_amdgcn_global_load_lds( \
    (const __attribute__((address_space(1))) void*)(gp),    \
    (__attribute__((address_space(3))) void*)(lp), 16, 0, 0)

__device__ __forceinline__ bf16x8 as_bf16x8(int4 v) { return __builtin_bit_cast(bf16x8, v); }
__device__ __forceinline__ u16 bf16_bits(float f) { return __builtin_bit_cast(u16, (__bf16)f); }

// Runtime dtype detect: f32-as-u16 low words have big exponent fields.
__device__ __forceinline__ bool detect_f32(const void* X) {
    const u16* x16 = (const u16*)X;
    int lane = threadIdx.x & 63;
    int hits = 0;
#pragma unroll
    for (int i = 0; i < 4; ++i) {
        u16 v = x16[lane * 4 + i];
        hits += (((v >> 7) & 0xFF) > 130) ? 1 : 0;
    }
    return __popcll(__ballot(hits > 0)) >= 8;
}

__device__ __forceinline__ bf16x8 load8(const void* p, size_t eoff, bool f32m) {
    if (!f32m) return as_bf16x8(*(const int4*)((const u16*)p + eoff));
    const float* f = (const float*)p + eoff;
    float4 a = *(const float4*)f;
    float4 b = *(const float4*)(f + 4);
    bf16x8 r;
    r[0] = (__bf16)a.x; r[1] = (__bf16)a.y; r[2] = (__bf16)a.z; r[3] = (__bf16)a.w;
    r[4] = (__bf16)b.x; r[5] = (__bf16)b.y; r[6] = (__bf16)b.z; r[7] = (__bf16)b.w;
    return r;
}

// ---------------- prep: 4 weight transposes (z=0..3) + X cvt (z=4) ----------
__global__ __launch_bounds__(256) void prep_all(const void* __restrict__ Wq,
                                                const void* __restrict__ Wk,
                                                const void* __restrict__ Wv,
                                                const void* __restrict__ Wo,
                                                const void* __restrict__ X,
                                                u16* __restrict__ Wt3,
                                                u16* __restrict__ Wot,
                                                u16* __restrict__ Xbf) {
    bool f32m = detect_f32(X);
    int z = blockIdx.z;
    if (z == 4) {
        int blk = blockIdx.y * 16 + blockIdx.x;
        size_t base = (size_t)blk * 16384 + threadIdx.x * 8;
#pragma unroll
        for (int i = 0; i < 8; ++i) {
            size_t eoff = base + (size_t)i * 2048;
            bf16x8 v = load8(X, eoff, f32m);
            *(int4*)(Xbf + eoff) = __builtin_bit_cast(int4, v);
        }
        return;
    }
    const void* in = (z == 0) ? Wq : (z == 1) ? Wk : (z == 2) ? Wv : Wo;
    u16* out = (z < 3) ? (Wt3 + (size_t)z * (1u << 20)) : Wot;
    __shared__ alignas(16) u16 T[64][TS];
    int r0 = blockIdx.y * 64, c0 = blockIdx.x * 64;
    int tr = threadIdx.x >> 3, tc8 = threadIdx.x & 7;
    bf16x8 v0 = load8(in, (size_t)(r0 + tr) * 1024 + c0 + tc8 * 8, f32m);
    bf16x8 v1 = load8(in, (size_t)(r0 + tr + 32) * 1024 + c0 + tc8 * 8, f32m);
    *(int4*)&T[tr][tc8 * 8]      = __builtin_bit_cast(int4, v0);
    *(int4*)&T[tr + 32][tc8 * 8] = __builtin_bit_cast(int4, v1);
    __syncthreads();
    for (int half = 0; half < 2; ++half) {
        int cr = tr + half * 32;
        u16 tmp[8];
#pragma unroll
        for (int i = 0; i < 8; ++i) tmp[i] = T[tc8 * 8 + i][cr];
        *(int4*)(out + (size_t)(c0 + cr) * 1024 + r0 + tc8 * 8) = *(int4*)tmp;
    }
}

// ---------------- 128x128-tile bf16 MFMA GEMM (QKV), XOR-swizzled LDS -------
// A: Xbf [4096][1024] bf16; Bt: Wqkv^T [3072][1024] bf16.  Pure GLD staging.
// 4 waves, each 64x64 subtile: 32 MFMA : 16 b128-reads per wave-iter.
// NOTE: keep default x-fastest block mapping -- it pins a 1MB A-slice per
// XCD (x mod 8 is y-invariant); R20's remap broke this (FETCH 14->36MB).
__global__ __launch_bounds__(256, 4) void gemm128(const u16* __restrict__ A,
                                                  const u16* __restrict__ Bt,
                                                  u16* __restrict__ Cq, u16* __restrict__ Ck,
                                                  u16* __restrict__ Cv) {
    __shared__ alignas(16) u16 As[128 * 64];
    __shared__ alignas(16) u16 Bs[128 * 64];
    const int K = 1024;
    int tid = threadIdx.x, wave = tid >> 6, lane = tid & 63;
    int quad = lane >> 4, l16 = lane & 15;
    int wrow = wave >> 1, wcol = wave & 1;
    int m0 = blockIdx.x * 128, n0 = blockIdx.y * 128;
    int rlane = lane >> 3, kc = lane & 7;
    int scol = (kc ^ rlane) * 8;          // swizzled source column (u16)

    f32x4 acc[4][4] = {};

    for (int k0 = 0; k0 < K; k0 += 64) {
        __syncthreads();
#pragma unroll
        for (int i = 0; i < 4; ++i) {
            int rc = wave * 4 + i;       // 16 chunks of 8 rows each
            GLD_LDS16(A  + (size_t)(m0 + rc * 8 + rlane) * K + k0 + scol, As + rc * 512);
            GLD_LDS16(Bt + (size_t)(n0 + rc * 8 + rlane) * K + k0 + scol, Bs + rc * 512);
        }
        __syncthreads();
#pragma unroll
        for (int ks = 0; ks < 2; ++ks) {
            bf16x8 af[4], bfr[4];
#pragma unroll
            for (int i = 0; i < 4; ++i) {
                int row = wrow * 64 + i * 16 + l16;
                af[i] = as_bf16x8(*(const int4*)(As + row * 64 + (((ks * 4 + quad) ^ (row & 7)) * 8)));
            }
#pragma unroll
            for (int j = 0; j < 4; ++j) {
                int row = wcol * 64 + j * 16 + l16;
                bfr[j] = as_bf16x8(*(const int4*)(Bs + row * 64 + (((ks * 4 + quad) ^ (row & 7)) * 8)));
            }
#pragma unroll
            for (int i = 0; i < 4; ++i)
#pragma unroll
                for (int j = 0; j < 4; ++j)
                    acc[i][j] = __builtin_amdgcn_mfma_f32_16x16x32_bf16(af[i], bfr[j], acc[i][j], 0, 0, 0);
        }
    }

#pragma unroll
    for (int i = 0; i < 4; ++i)
#pragma unroll
        for (int j = 0; j < 4; ++j)
#pragma unroll
            for (int r = 0; r < 4; ++r) {
                int m = m0 + wrow * 64 + i * 16 + quad * 4 + r;
                int n = n0 + wcol * 64 + j * 16 + l16;
                float f = acc[i][j][r];
                if (n < 1024)       Cq[(size_t)m * 1024 + n] = bf16_bits(f);
                else if (n < 2048)  Ck[(size_t)m * 1024 + n - 1024] = bf16_bits(f);
                else {
                    int n2 = n - 2048;
                    int bh = ((m >> 11) << 4) | (n2 >> 6), d = n2 & 63, t = m & 2047;
                    Cv[(((size_t)bh * 64 + d) << 11) + t] = bf16_bits(f);
                }
            }
}

// ---------------- 64x128-tile GEMM (out-proj), R16: BK=128 ------------------
__global__ __launch_bounds__(256, 4) void gemm_out(const u16* __restrict__ A,
                                                   const u16* __restrict__ Bt,
                                                   void* __restrict__ Cout,
                                                   const void* __restrict__ Xdet) {
    bool f32m = detect_f32(Xdet);
    __shared__ alignas(16) u16 As[64 * 128];    // 16 KB
    __shared__ alignas(16) u16 Bs[128 * 128];   // 32 KB
    const int K = 1024;
    int tid = threadIdx.x, wave = tid >> 6, lane = tid & 63;
    int quad = lane >> 4, l16 = lane & 15;
    int wrow = wave & 1, wcol = wave >> 1;
    int m0 = blockIdx.x * 64, n0 = blockIdx.y * 128;
    int rlane4 = lane >> 4, kc16 = lane & 15;   // staging: 4 rows x 16 chunks

    f32x4 acc[2][4] = {};

    for (int k0 = 0; k0 < K; k0 += 128) {
        __syncthreads();
#pragma unroll
        for (int i = 0; i < 8; ++i) {           // B: 128 rows, 4 per GLD
            int rb = wave * 32 + i * 4;
            int grow = rb + rlane4;
            int gch = kc16 ^ (grow & 15);
            GLD_LDS16(Bt + (size_t)(n0 + grow) * K + k0 + gch * 8, Bs + rb * 128);
        }
#pragma unroll
        for (int i = 0; i < 4; ++i) {           // A: 64 rows, 4 per GLD
            int rb = wave * 16 + i * 4;
            int grow = rb + rlane4;
            int gch = kc16 ^ (grow & 15);
            GLD_LDS16(A + (size_t)(m0 + grow) * K + k0 + gch * 8, As + rb * 128);
        }
        __syncthreads();
#pragma unroll
        for (int ks = 0; ks < 4; ++ks) {
            bf16x8 af[2], bfr[4];
#pragma unroll
            for (int i = 0; i < 2; ++i) {
                int row = wrow * 32 + i * 16 + l16;
                af[i] = as_bf16x8(*(const int4*)(As + row * 128 + (((ks * 4 + quad) ^ (row & 15)) * 8)));
            }
#pragma unroll
            for (int j = 0; j < 4; ++j) {
                int row = wcol * 64 + j * 16 + l16;
                bfr[j] = as_bf16x8(*(const int4*)(Bs + row * 128 + (((ks * 4 + quad) ^ (row & 15)) * 8)));
            }
#pragma unroll
            for (int i = 0; i < 2; ++i)
#pragma unroll
                for (int j = 0; j < 4; ++j)
                    acc[i][j] = __builtin_amdgcn_mfma_f32_16x16x32_bf16(af[i], bfr[j], acc[i][j], 0, 0, 0);
        }
    }

#pragma unroll
    for (int i = 0; i < 2; ++i)
#pragma unroll
        for (int j = 0; j < 4; ++j)
#pragma unroll
            for (int r = 0; r < 4; ++r) {
                int m = m0 + wrow * 32 + i * 16 + quad * 4 + r;
                int n = n0 + wcol * 64 + j * 16 + l16;
                float f = acc[i][j][r];
                if (f32m) ((float*)Cout)[(size_t)m * 1024 + n] = f;
                else      ((u16*)Cout)[(size_t)m * 1024 + n] = bf16_bits(f);
            }
}

// ---------------- flash attention (R22: R18 dbuf + conflict-free PSQ=56) ----
// Per tile: issue next tile's 4 GLDs -> compute (4 groups of {QK 2nt ->
// softmax -> Ps -> PV 1ks}) -> ONE __syncthreads (its vmcnt(0) drain is
// hidden under the compute phase).  Buffers are separate named arrays with
// compile-time selection (2x-unrolled j2 loop).

#define STAGE_TILE(KSBUF, VSBUF, T0)                                           \
    {                                                                          \
        _Pragma("unroll")                                                      \
        for (int i_ = 0; i_ < 2; ++i_) {                                       \
            int rb_ = (wave * 2 + i_) * 8;                                     \
            int grow_ = rb_ + kr4;                                             \
            int gch_ = kc ^ (grow_ & 7);                                       \
            GLD_LDS16(kbase + (size_t)((T0) + grow_) * 1024 + gch_ * 8,        \
                      KSBUF + rb_ * 64);                                       \
        }                                                                      \
        _Pragma("unroll")                                                      \
        for (int i_ = 0; i_ < 2; ++i_) {                                       \
            int rb_ = (wave * 2 + i_) * 4;                                     \
            int grow_ = rb_ + vr4;                                             \
            int gch_ = vc ^ (grow_ & 15);                                      \
            GLD_LDS16(vbase + (size_t)grow_ * 2048 + (T0) + gch_ * 8,          \
                      VSBUF + rb_ * 128);                                      \
        }                                                                      \
    }

#define COMPUTE_TILE(KS, VS, DIAG, NTC)                                        \
    {                                                                          \
        _Pragma("unroll")                                                      \
        for (int g = 0; g < 4; ++g) {                                          \
            if (2 * g >= (NTC)) continue;                                      \
            f32x4 sg0, sg1;                                                    \
            __builtin_amdgcn_s_setprio(1);                                     \
            _Pragma("unroll")                                                  \
            for (int h2 = 0; h2 < 2; ++h2) {                                   \
                int nt = 2 * g + h2;                                           \
                f32x4 a = {};                                                  \
                if ((DIAG) && nt > wave) {                                     \
                    a[0] = NEG_INF; a[1] = NEG_INF;                            \
                    a[2] = NEG_INF; a[3] = NEG_INF;                            \
                } else {                                                       \
                    int row = nt * 16 + l16;                                   \
                    int sw = row & 7;                                          \
                    bf16x8 b0 = as_bf16x8(*(const int4*)((KS) + row * 64 + ((quad ^ sw) * 8)));       \
                    a = __builtin_amdgcn_mfma_f32_16x16x32_bf16(b0, qa0, a, 0, 0, 0);                 \
                    bf16x8 b1 = as_bf16x8(*(const int4*)((KS) + row * 64 + (((4 + quad) ^ sw) * 8))); \
                    a = __builtin_amdgcn_mfma_f32_16x16x32_bf16(b1, qa1, a, 0, 0, 0);                 \
                    a = a * SC_LOG2;                                           \
                    if ((DIAG) && nt == wave) {                                \
                        _Pragma("unroll")                                      \
                        for (int r = 0; r < 4; ++r)                            \
                            if (quad * 4 + r > l16) a[r] = NEG_INF;            \
                    }                                                          \
                }                                                              \
                if (h2 == 0) sg0 = a; else sg1 = a;                            \
            }                                                                  \
            __builtin_amdgcn_s_setprio(0);                                     \
            _Pragma("unroll")                                                  \
            for (int h2 = 0; h2 < 2; ++h2) {                                   \
                f32x4 sv = h2 ? sg1 : sg0;                                     \
                u16x4 pk;                                                      \
                float ps4 = 0.0f;                                              \
                _Pragma("unroll")                                              \
                for (int r = 0; r < 4; ++r) {                                  \
                    float p = EXP2(sv[r]);                                     \
                    ps4 += p;                                                  \
                    pk[r] = bf16_bits(p);                                      \
                }                                                              \
                psum += ps4;                                                   \
                *(u16x4*)(Ps + prow + h2 * 16 + quad * 4) = pk;                \
            }                                                                  \
            __builtin_amdgcn_s_setprio(1);                                     \
            {                                                                  \
                bf16x8 pa = as_bf16x8(*(const int4*)(Ps + prow + quad * 8));   \
                _Pragma("unroll")                                              \
                for (int d4 = 0; d4 < 4; ++d4) {                               \
                    int vrow = d4 * 16 + l16;                                  \
                    bf16x8 vb = as_bf16x8(*(const int4*)((VS) + vrow * 128 + (((g * 4 + quad) ^ l16) * 8))); \
                    o[d4] = __builtin_amdgcn_mfma_f32_16x16x32_bf16(pa, vb, o[d4], 0, 0, 0);          \
                }                                                              \
            }                                                                  \
            __builtin_amdgcn_s_setprio(0);                                     \
        }                                                                      \
    }

__global__ __launch_bounds__(512, 4) void attn_kernel(const u16* __restrict__ Qb,
                                                      const u16* __restrict__ Kb,
                                                      const u16* __restrict__ Vt,
                                                      u16* __restrict__ Ab) {
    __shared__ alignas(16) u16 Ks0[128 * 64];  // swizzled [kv][d], buffer 0
    __shared__ alignas(16) u16 Ks1[128 * 64];  // buffer 1
    __shared__ alignas(16) u16 Vs0[64 * 128];  // swizzled [d][t], buffer 0
    __shared__ alignas(16) u16 Vs1[64 * 128];  // buffer 1
    __shared__ alignas(16) u16 Ps[128 * PSQ];  // [q 128][kv 32] quarter, padded

    int tid = threadIdx.x, wave = tid >> 6, lane = tid & 63;
    int quad = lane >> 4, l16 = lane & 15;
    int bh = blockIdx.x;                 // x fastest => heavy-J blocks first
    // Complementary pairing: resident CU pairs (i, i+256) sum to 17 kv-iters.
    int J = (blockIdx.y < 8) ? (15 - (int)blockIdx.y) : ((int)blockIdx.y - 8);
    int b = bh >> 4, h = bh & 15;
    int q0 = J * 128;
    int kr4 = lane >> 3, kc = lane & 7;   // K staging: 8 rows x 8 chunks
    int vr4 = lane >> 4, vc = lane & 15;  // V staging: 4 rows x 16 chunks

    const u16* qrow = Qb + (size_t)(b * 2048 + q0 + wave * 16 + l16) * 1024 + h * 64;
    bf16x8 qa0 = as_bf16x8(*(const int4*)(qrow + quad * 8));
    bf16x8 qa1 = as_bf16x8(*(const int4*)(qrow + 32 + quad * 8));

    f32x4 o[4] = {};
    float psum = 0.0f;                   // lane-local: q = wave*16+l16
    int prow = (wave * 16 + l16) * PSQ;

    const u16* kbase = Kb + (size_t)(b * 2048) * 1024 + h * 64;
    const u16* vbase = Vt + (size_t)bh * 64 * 2048;

    // prologue: tile 0 into buffer 0 (drain exposed once).
    STAGE_TILE(Ks0, Vs0, 0);
    __syncthreads();

    for (int j2 = 0; j2 <= J; j2 += 2) {
        // ---- sub-iter A: compute tile j2 from buf0; prefetch j2+1 -> buf1
        if (j2 + 1 <= J) STAGE_TILE(Ks1, Vs1, (j2 + 1) * 128);
        {
            bool diag = (j2 == J);
            int ntc = diag ? ((wave & ~1) + 2) : 8;
            COMPUTE_TILE(Ks0, Vs0, diag, ntc);
        }
        __syncthreads();                 // buf1 loads done; buf0 free
        if (j2 + 1 > J) break;
        // ---- sub-iter B: compute tile j2+1 from buf1; prefetch j2+2 -> buf0
        if (j2 + 2 <= J) STAGE_TILE(Ks0, Vs0, (j2 + 2) * 128);
        {
            bool diag = (j2 + 1 == J);
            int ntc = diag ? ((wave & ~1) + 2) : 8;
            COMPUTE_TILE(Ks1, Vs1, diag, ntc);
        }
        __syncthreads();                 // buf0 loads done; buf1 free
    }

    // denominators: reduce across quads (kv partition), redistribute to rows.
    psum += __shfl_xor(psum, 16);
    psum += __shfl_xor(psum, 32);        // now full denom for q = wave*16+l16

    u16* arow = Ab + (size_t)(b * 2048 + q0 + wave * 16) * 1024 + h * 64;
#pragma unroll
    for (int r = 0; r < 4; ++r) {
        float dn = __shfl(psum, quad * 4 + r, 16);   // denom for q row quad*4+r
        float inv = 1.0f / dn;
#pragma unroll
        for (int d4 = 0; d4 < 4; ++d4)
            arow[(quad * 4 + r) * 1024 + d4 * 16 + l16] = bf16_bits(o[d4][r] * inv);
    }
}

// ---------------------------------------------------------------------------
extern "C" void kernel_launch(void* const* d_in, const int* in_sizes, int n_in,
                              void* d_out, int out_size, void* d_ws, size_t ws_size,
                              hipStream_t stream) {
    (void)in_sizes; (void)n_in; (void)out_size; (void)ws_size;
    const void* X  = d_in[0];
    const void* Wq = d_in[1];
    const void* Wk = d_in[2];
    const void* Wv = d_in[3];
    const void* Wo = d_in[4];
    u16* ws16 = (u16*)d_ws;
    const size_t M1 = 1u << 20;
    u16* Xbf = ws16 + 0 * M1;        // [0,4M)
    u16* Wt3 = ws16 + 4 * M1;        // [4M,7M)
    u16* Qb  = ws16 + 7 * M1;
    u16* Kb  = ws16 + 11 * M1;
    u16* Vt  = ws16 + 15 * M1;
    u16* Wot = ws16 + 19 * M1;
    u16* Ab  = ws16 + 0 * M1;        // aliases Xbf (dead after QKV GEMM)

    prep_all<<<dim3(16, 16, 5), 256, 0, stream>>>(Wq, Wk, Wv, Wo, X, Wt3, Wot, Xbf);
    gemm128<<<dim3(32, 24), 256, 0, stream>>>(Xbf, Wt3, Qb, Kb, Vt);
    attn_kernel<<<dim3(32, 16), 512, 0, stream>>>(Qb, Kb, Vt, Ab);
    gemm_out<<<dim3(64, 8), 256, 0, stream>>>(Ab, Wot, d_out, X);
}

// Round 11
// 168.398 us; speedup vs baseline: 1.0337x; 1.0337x over previous
//
#include <hip/hip_runtime.h>
#include <hip/hip_bf16.h>

// ---------------------------------------------------------------------------
// Causal MHA forward.  B=2, T=2048, H=16, Dk=64, D=1024.  Inputs float32;
// internal pipeline bf16 MFMA.
// R24: attn KVBLK 128->256 (halve tile-visits: 19->9 per CU at ~0.4-0.6us
//     fixed cost each, per R13/R19 regression arithmetic).  Enabled by the
//     R22-verified grouped compute (QK 2-chunk -> softmax -> quarter-Ps
//     PSQ=56 -> PV pair), so LDS = 32K Ks + 32K Vs + 14.3K Ps = 78.3 KB ->
//     2 blocks/CU kept.  Single-buffer 2-barrier loop (dbuf measured neutral
//     twice: R18/R22).  Masking in 16-kv chunks: lim = 8J + wave - 16*j2
//     (R19-verified pattern); off-diag lim>=16 -> no mask.  V staged
//     2 rows/GLD (lane>>5, lane&31), same row-keyed XOR (row&15==l16
//     cancellation proven in R16).  Diag over-stage (<=128 rows) stays
//     in-bounds (max row 2047) and only adds ~4MB L2 reads.
//     prep/gemm128 frozen at R12 (keep default x-fastest mapping: 1MB
//     A-slice/XCD -- R20 lesson); gemm_out frozen at R16.
//     Noise calibration (R21): same source varies ±4us across pods.
//     launch_bounds min-waves MUST stay 4 (6 spilled twice: R6, R7).
// Workspace (u16 elements, 1M = 2^20), 40 MB:
//   [0,4M)   Xbf [4096][1024] bf16      (Ab aliases this after QKV)
//   [4M,7M)  Wqkv^T (3 x [1024][1024])
//   [7M,11M) Q   [11M,15M) K   [15M,19M) V^T [32][64][2048]
//   [19M,20M) Wo^T
// ---------------------------------------------------------------------------

typedef unsigned short u16;
typedef __bf16 bf16x8 __attribute__((ext_vector_type(8)));
typedef float f32x4 __attribute__((ext_vector_type(4)));
typedef u16 u16x4 __attribute__((ext_vector_type(4)));

#define TS 72               // padded LDS stride (transpose)
#define PSQ 56              // quarter P-tile stride: 32 cols + 24 pad
                            // (112B row: 2-way banks = free; 16B-aligned)
#define NEG_INF (-1e30f)
#define SC_LOG2 0.1803368801f   // log2(e)/8  (exp2-domain softmax scale)

#if __has_builtin(__builtin_amdgcn_exp2f)
#define EXP2(x) __builtin_amdgcn_exp2f(x)
#else
#define EXP2(x) exp2f(x)
#endif

#define GLD_LDS16(gp, lp) __builtin_amdgcn_global_load_lds( \
    (const __attribute__((address_space(1))) void*)(gp),    \
    (__attribute__((address_space(3))) void*)(lp), 16, 0, 0)

__device__ __forceinline__ bf16x8 as_bf16x8(int4 v) { return __builtin_bit_cast(bf16x8, v); }
__device__ __forceinline__ u16 bf16_bits(float f) { return __builtin_bit_cast(u16, (__bf16)f); }

// Runtime dtype detect: f32-as-u16 low words have big exponent fields.
__device__ __forceinline__ bool detect_f32(const void* X) {
    const u16* x16 = (const u16*)X;
    int lane = threadIdx.x & 63;
    int hits = 0;
#pragma unroll
    for (int i = 0; i < 4; ++i) {
        u16 v = x16[lane * 4 + i];
        hits += (((v >> 7) & 0xFF) > 130) ? 1 : 0;
    }
    return __popcll(__ballot(hits > 0)) >= 8;
}

__device__ __forceinline__ bf16x8 load8(const void* p, size_t eoff, bool f32m) {
    if (!f32m) return as_bf16x8(*(const int4*)((const u16*)p + eoff));
    const float* f = (const float*)p + eoff;
    float4 a = *(const float4*)f;
    float4 b = *(const float4*)(f + 4);
    bf16x8 r;
    r[0] = (__bf16)a.x; r[1] = (__bf16)a.y; r[2] = (__bf16)a.z; r[3] = (__bf16)a.w;
    r[4] = (__bf16)b.x; r[5] = (__bf16)b.y; r[6] = (__bf16)b.z; r[7] = (__bf16)b.w;
    return r;
}

// ---------------- prep: 4 weight transposes (z=0..3) + X cvt (z=4) ----------
__global__ __launch_bounds__(256) void prep_all(const void* __restrict__ Wq,
                                                const void* __restrict__ Wk,
                                                const void* __restrict__ Wv,
                                                const void* __restrict__ Wo,
                                                const void* __restrict__ X,
                                                u16* __restrict__ Wt3,
                                                u16* __restrict__ Wot,
                                                u16* __restrict__ Xbf) {
    bool f32m = detect_f32(X);
    int z = blockIdx.z;
    if (z == 4) {
        int blk = blockIdx.y * 16 + blockIdx.x;
        size_t base = (size_t)blk * 16384 + threadIdx.x * 8;
#pragma unroll
        for (int i = 0; i < 8; ++i) {
            size_t eoff = base + (size_t)i * 2048;
            bf16x8 v = load8(X, eoff, f32m);
            *(int4*)(Xbf + eoff) = __builtin_bit_cast(int4, v);
        }
        return;
    }
    const void* in = (z == 0) ? Wq : (z == 1) ? Wk : (z == 2) ? Wv : Wo;
    u16* out = (z < 3) ? (Wt3 + (size_t)z * (1u << 20)) : Wot;
    __shared__ alignas(16) u16 T[64][TS];
    int r0 = blockIdx.y * 64, c0 = blockIdx.x * 64;
    int tr = threadIdx.x >> 3, tc8 = threadIdx.x & 7;
    bf16x8 v0 = load8(in, (size_t)(r0 + tr) * 1024 + c0 + tc8 * 8, f32m);
    bf16x8 v1 = load8(in, (size_t)(r0 + tr + 32) * 1024 + c0 + tc8 * 8, f32m);
    *(int4*)&T[tr][tc8 * 8]      = __builtin_bit_cast(int4, v0);
    *(int4*)&T[tr + 32][tc8 * 8] = __builtin_bit_cast(int4, v1);
    __syncthreads();
    for (int half = 0; half < 2; ++half) {
        int cr = tr + half * 32;
        u16 tmp[8];
#pragma unroll
        for (int i = 0; i < 8; ++i) tmp[i] = T[tc8 * 8 + i][cr];
        *(int4*)(out + (size_t)(c0 + cr) * 1024 + r0 + tc8 * 8) = *(int4*)tmp;
    }
}

// ---------------- 128x128-tile bf16 MFMA GEMM (QKV), XOR-swizzled LDS -------
// A: Xbf [4096][1024] bf16; Bt: Wqkv^T [3072][1024] bf16.  Pure GLD staging.
// 4 waves, each 64x64 subtile: 32 MFMA : 16 b128-reads per wave-iter.
// NOTE: keep default x-fastest block mapping -- it pins a 1MB A-slice per
// XCD (x mod 8 is y-invariant); R20's remap broke this (FETCH 14->36MB).
__global__ __launch_bounds__(256, 4) void gemm128(const u16* __restrict__ A,
                                                  const u16* __restrict__ Bt,
                                                  u16* __restrict__ Cq, u16* __restrict__ Ck,
                                                  u16* __restrict__ Cv) {
    __shared__ alignas(16) u16 As[128 * 64];
    __shared__ alignas(16) u16 Bs[128 * 64];
    const int K = 1024;
    int tid = threadIdx.x, wave = tid >> 6, lane = tid & 63;
    int quad = lane >> 4, l16 = lane & 15;
    int wrow = wave >> 1, wcol = wave & 1;
    int m0 = blockIdx.x * 128, n0 = blockIdx.y * 128;
    int rlane = lane >> 3, kc = lane & 7;
    int scol = (kc ^ rlane) * 8;          // swizzled source column (u16)

    f32x4 acc[4][4] = {};

    for (int k0 = 0; k0 < K; k0 += 64) {
        __syncthreads();
#pragma unroll
        for (int i = 0; i < 4; ++i) {
            int rc = wave * 4 + i;       // 16 chunks of 8 rows each
            GLD_LDS16(A  + (size_t)(m0 + rc * 8 + rlane) * K + k0 + scol, As + rc * 512);
            GLD_LDS16(Bt + (size_t)(n0 + rc * 8 + rlane) * K + k0 + scol, Bs + rc * 512);
        }
        __syncthreads();
#pragma unroll
        for (int ks = 0; ks < 2; ++ks) {
            bf16x8 af[4], bfr[4];
#pragma unroll
            for (int i = 0; i < 4; ++i) {
                int row = wrow * 64 + i * 16 + l16;
                af[i] = as_bf16x8(*(const int4*)(As + row * 64 + (((ks * 4 + quad) ^ (row & 7)) * 8)));
            }
#pragma unroll
            for (int j = 0; j < 4; ++j) {
                int row = wcol * 64 + j * 16 + l16;
                bfr[j] = as_bf16x8(*(const int4*)(Bs + row * 64 + (((ks * 4 + quad) ^ (row & 7)) * 8)));
            }
#pragma unroll
            for (int i = 0; i < 4; ++i)
#pragma unroll
                for (int j = 0; j < 4; ++j)
                    acc[i][j] = __builtin_amdgcn_mfma_f32_16x16x32_bf16(af[i], bfr[j], acc[i][j], 0, 0, 0);
        }
    }

#pragma unroll
    for (int i = 0; i < 4; ++i)
#pragma unroll
        for (int j = 0; j < 4; ++j)
#pragma unroll
            for (int r = 0; r < 4; ++r) {
                int m = m0 + wrow * 64 + i * 16 + quad * 4 + r;
                int n = n0 + wcol * 64 + j * 16 + l16;
                float f = acc[i][j][r];
                if (n < 1024)       Cq[(size_t)m * 1024 + n] = bf16_bits(f);
                else if (n < 2048)  Ck[(size_t)m * 1024 + n - 1024] = bf16_bits(f);
                else {
                    int n2 = n - 2048;
                    int bh = ((m >> 11) << 4) | (n2 >> 6), d = n2 & 63, t = m & 2047;
                    Cv[(((size_t)bh * 64 + d) << 11) + t] = bf16_bits(f);
                }
            }
}

// ---------------- 64x128-tile GEMM (out-proj), R16: BK=128 ------------------
__global__ __launch_bounds__(256, 4) void gemm_out(const u16* __restrict__ A,
                                                   const u16* __restrict__ Bt,
                                                   void* __restrict__ Cout,
                                                   const void* __restrict__ Xdet) {
    bool f32m = detect_f32(Xdet);
    __shared__ alignas(16) u16 As[64 * 128];    // 16 KB
    __shared__ alignas(16) u16 Bs[128 * 128];   // 32 KB
    const int K = 1024;
    int tid = threadIdx.x, wave = tid >> 6, lane = tid & 63;
    int quad = lane >> 4, l16 = lane & 15;
    int wrow = wave & 1, wcol = wave >> 1;
    int m0 = blockIdx.x * 64, n0 = blockIdx.y * 128;
    int rlane4 = lane >> 4, kc16 = lane & 15;   // staging: 4 rows x 16 chunks

    f32x4 acc[2][4] = {};

    for (int k0 = 0; k0 < K; k0 += 128) {
        __syncthreads();
#pragma unroll
        for (int i = 0; i < 8; ++i) {           // B: 128 rows, 4 per GLD
            int rb = wave * 32 + i * 4;
            int grow = rb + rlane4;
            int gch = kc16 ^ (grow & 15);
            GLD_LDS16(Bt + (size_t)(n0 + grow) * K + k0 + gch * 8, Bs + rb * 128);
        }
#pragma unroll
        for (int i = 0; i < 4; ++i) {           // A: 64 rows, 4 per GLD
            int rb = wave * 16 + i * 4;
            int grow = rb + rlane4;
            int gch = kc16 ^ (grow & 15);
            GLD_LDS16(A + (size_t)(m0 + grow) * K + k0 + gch * 8, As + rb * 128);
        }
        __syncthreads();
#pragma unroll
        for (int ks = 0; ks < 4; ++ks) {
            bf16x8 af[2], bfr[4];
#pragma unroll
            for (int i = 0; i < 2; ++i) {
                int row = wrow * 32 + i * 16 + l16;
                af[i] = as_bf16x8(*(const int4*)(As + row * 128 + (((ks * 4 + quad) ^ (row & 15)) * 8)));
            }
#pragma unroll
            for (int j = 0; j < 4; ++j) {
                int row = wcol * 64 + j * 16 + l16;
                bfr[j] = as_bf16x8(*(const int4*)(Bs + row * 128 + (((ks * 4 + quad) ^ (row & 15)) * 8)));
            }
#pragma unroll
            for (int i = 0; i < 2; ++i)
#pragma unroll
                for (int j = 0; j < 4; ++j)
                    acc[i][j] = __builtin_amdgcn_mfma_f32_16x16x32_bf16(af[i], bfr[j], acc[i][j], 0, 0, 0);
        }
    }

#pragma unroll
    for (int i = 0; i < 2; ++i)
#pragma unroll
        for (int j = 0; j < 4; ++j)
#pragma unroll
            for (int r = 0; r < 4; ++r) {
                int m = m0 + wrow * 32 + i * 16 + quad * 4 + r;
                int n = n0 + wcol * 64 + j * 16 + l16;
                float f = acc[i][j][r];
                if (f32m) ((float*)Cout)[(size_t)m * 1024 + n] = f;
                else      ((u16*)Cout)[(size_t)m * 1024 + n] = bf16_bits(f);
            }
}

// ---------------- flash attention (R24: KVBLK=256, grouped quarter-Ps) ------
// Per 256-kv tile: 2 barriers + 8 GLD/thread staging, then 8 groups of
// {QK 2 chunks -> exp2 -> Ps[128][56] -> PV 1 pair}.  Masking in 16-kv
// chunks: lim = 8J + wave - 16*j2; nt<lim full, ==lim partial (quad*4+r >
// l16), >lim NEG_INF (zero P); off-diag tiles have lim>=16 (no mask).
__global__ __launch_bounds__(512, 4) void attn_kernel(const u16* __restrict__ Qb,
                                                      const u16* __restrict__ Kb,
                                                      const u16* __restrict__ Vt,
                                                      u16* __restrict__ Ab) {
    __shared__ alignas(16) u16 Ks[256 * 64];   // swizzled [kv][d]   32 KB
    __shared__ alignas(16) u16 Vs[64 * 256];   // swizzled [d][t]    32 KB
    __shared__ alignas(16) u16 Ps[128 * PSQ];  // quarter P, 14.3 KB

    int tid = threadIdx.x, wave = tid >> 6, lane = tid & 63;
    int quad = lane >> 4, l16 = lane & 15;
    int bh = blockIdx.x;                 // x fastest => heavy-J blocks first
    // Complementary pairing: resident CU pairs (i, i+256) balance load.
    int J = (blockIdx.y < 8) ? (15 - (int)blockIdx.y) : ((int)blockIdx.y - 8);
    int b = bh >> 4, h = bh & 15;
    int q0 = J * 128;
    int kr4 = lane >> 3, kc = lane & 7;   // K staging: 8 rows x 8 chunks
    int vr2 = lane >> 5, vc32 = lane & 31;// V staging: 2 rows x 32 chunks

    const u16* qrow = Qb + (size_t)(b * 2048 + q0 + wave * 16 + l16) * 1024 + h * 64;
    bf16x8 qa0 = as_bf16x8(*(const int4*)(qrow + quad * 8));
    bf16x8 qa1 = as_bf16x8(*(const int4*)(qrow + 32 + quad * 8));

    f32x4 o[4] = {};
    float psum = 0.0f;                   // lane-local: q = wave*16+l16
    int prow = (wave * 16 + l16) * PSQ;

    const u16* kbase = Kb + (size_t)(b * 2048) * 1024 + h * 64;
    const u16* vbase = Vt + (size_t)bh * 64 * 2048;

    int NJ = (J + 2) >> 1;               // number of 256-wide kv tiles

    for (int j2 = 0; j2 < NJ; ++j2) {
        int t0 = j2 * 256;
        __syncthreads();
#pragma unroll
        for (int i = 0; i < 4; ++i) {        // K: 256 rows, 8 per GLD
            int rb = wave * 32 + i * 8;
            int grow = rb + kr4;
            int gch = kc ^ (grow & 7);
            GLD_LDS16(kbase + (size_t)(t0 + grow) * 1024 + gch * 8, Ks + rb * 64);
        }
#pragma unroll
        for (int i = 0; i < 4; ++i) {        // V: 64 rows x 256, 2 rows per GLD
            int rb = wave * 8 + i * 2;
            int grow = rb + vr2;
            int gch = vc32 ^ (grow & 15);
            GLD_LDS16(vbase + (size_t)grow * 2048 + t0 + gch * 8, Vs + rb * 256);
        }
        __syncthreads();

        int lim = 8 * J + wave - 16 * j2;    // diag chunk (>=16 off-diag)
        int ntc = (lim + 2) & ~1;
        if (ntc > 16) ntc = 16;

#pragma unroll
        for (int g = 0; g < 8; ++g) {
            if (2 * g >= ntc) continue;
            f32x4 sg0, sg1;
            __builtin_amdgcn_s_setprio(1);
#pragma unroll
            for (int h2 = 0; h2 < 2; ++h2) {
                int nt = 2 * g + h2;
                f32x4 a = {};
                if (nt > lim) {
                    a[0] = NEG_INF; a[1] = NEG_INF; a[2] = NEG_INF; a[3] = NEG_INF;
                } else {
                    int row = nt * 16 + l16;
                    int sw = row & 7;
                    bf16x8 b0 = as_bf16x8(*(const int4*)(Ks + row * 64 + ((quad ^ sw) * 8)));
                    a = __builtin_amdgcn_mfma_f32_16x16x32_bf16(b0, qa0, a, 0, 0, 0);
                    bf16x8 b1 = as_bf16x8(*(const int4*)(Ks + row * 64 + (((4 + quad) ^ sw) * 8)));
                    a = __builtin_amdgcn_mfma_f32_16x16x32_bf16(b1, qa1, a, 0, 0, 0);
                    a = a * SC_LOG2;
                    if (nt == lim) {
#pragma unroll
                        for (int r = 0; r < 4; ++r)
                            if (quad * 4 + r > l16) a[r] = NEG_INF;
                    }
                }
                if (h2 == 0) sg0 = a; else sg1 = a;
            }
            __builtin_amdgcn_s_setprio(0);

            // softmax: lane-local; one ds_write_b64 per chunk.
#pragma unroll
            for (int h2 = 0; h2 < 2; ++h2) {
                f32x4 sv = h2 ? sg1 : sg0;
                u16x4 pk;
                float ps4 = 0.0f;
#pragma unroll
                for (int r = 0; r < 4; ++r) {
                    float p = EXP2(sv[r]);
                    ps4 += p;
                    pk[r] = bf16_bits(p);
                }
                psum += ps4;
                *(u16x4*)(Ps + prow + h2 * 16 + quad * 4) = pk;
            }

            // PV: chunk pair (2g, 2g+1) = V chunks g*4+quad.
            __builtin_amdgcn_s_setprio(1);
            {
                bf16x8 pa = as_bf16x8(*(const int4*)(Ps + prow + quad * 8));
#pragma unroll
                for (int d4 = 0; d4 < 4; ++d4) {
                    int vrow = d4 * 16 + l16;
                    bf16x8 vb = as_bf16x8(*(const int4*)(Vs + vrow * 256 + (((g * 4 + quad) ^ l16) * 8)));
                    o[d4] = __builtin_amdgcn_mfma_f32_16x16x32_bf16(pa, vb, o[d4], 0, 0, 0);
                }
            }
            __builtin_amdgcn_s_setprio(0);
        }
    }

    // denominators: reduce across quads (kv partition), redistribute to rows.
    psum += __shfl_xor(psum, 16);
    psum += __shfl_xor(psum, 32);        // now full denom for q = wave*16+l16

    u16* arow = Ab + (size_t)(b * 2048 + q0 + wave * 16) * 1024 + h * 64;
#pragma unroll
    for (int r = 0; r < 4; ++r) {
        float dn = __shfl(psum, quad * 4 + r, 16);   // denom for q row quad*4+r
        float inv = 1.0f / dn;
#pragma unroll
        for (int d4 = 0; d4 < 4; ++d4)
            arow[(quad * 4 + r) * 1024 + d4 * 16 + l16] = bf16_bits(o[d4][r] * inv);
    }
}

// ---------------------------------------------------------------------------
extern "C" void kernel_launch(void* const* d_in, const int* in_sizes, int n_in,
                              void* d_out, int out_size, void* d_ws, size_t ws_size,
                              hipStream_t stream) {
    (void)in_sizes; (void)n_in; (void)out_size; (void)ws_size;
    const void* X  = d_in[0];
    const void* Wq = d_in[1];
    const void* Wk = d_in[2];
    const void* Wv = d_in[3];
    const void* Wo = d_in[4];
    u16* ws16 = (u16*)d_ws;
    const size_t M1 = 1u << 20;
    u16* Xbf = ws16 + 0 * M1;        // [0,4M)
    u16* Wt3 = ws16 + 4 * M1;        // [4M,7M)
    u16* Qb  = ws16 + 7 * M1;
    u16* Kb  = ws16 + 11 * M1;
    u16* Vt  = ws16 + 15 * M1;
    u16* Wot = ws16 + 19 * M1;
    u16* Ab  = ws16 + 0 * M1;        // aliases Xbf (dead after QKV GEMM)

    prep_all<<<dim3(16, 16, 5), 256, 0, stream>>>(Wq, Wk, Wv, Wo, X, Wt3, Wot, Xbf);
    gemm128<<<dim3(32, 24), 256, 0, stream>>>(Xbf, Wt3, Qb, Kb, Vt);
    attn_kernel<<<dim3(32, 16), 512, 0, stream>>>(Qb, Kb, Vt, Ab);
    gemm_out<<<dim3(64, 8), 256, 0, stream>>>(Ab, Wot, d_out, X);
}